// Round 7
// baseline (495.981 us; speedup 1.0000x reference)
//
#include <hip/hip_runtime.h>
#include <hip/hip_cooperative_groups.h>
#include <math.h>
#include <type_traits>

namespace cg = cooperative_groups;

#define DEV __device__ __forceinline__

DEV float gelu_exact(float x) {
    return 0.5f * x * (1.0f + erff(x * 0.70710678118654752f));
}

DEV float dot4(const float4 a, const float4 b) {
    return a.x * b.x + a.y * b.y + a.z * b.z + a.w * b.w;
}

// ================= shared phase implementations =================

// ---- mask row i: cosine-sim threshold -> 8 u64 words ----
DEV void mask_row(const float* __restrict__ emb,
                  unsigned long long* __restrict__ maskw, int i, int tid) {
    float ei[8], ej[8];
    float si = 0.f, sj = 0.f;
#pragma unroll
    for (int e = 0; e < 8; ++e) { ei[e] = emb[i * 8 + e]; si += ei[e] * ei[e]; }
    const int jj = (tid < 500) ? tid : 0;
#pragma unroll
    for (int e = 0; e < 8; ++e) { ej[e] = emb[jj * 8 + e]; sj += ej[e] * ej[e]; }
    const float ri = 1.0f / sqrtf(si);
    const float rj = 1.0f / sqrtf(sj);
    float dot = 0.f;
#pragma unroll
    for (int e = 0; e < 8; ++e) dot += (ei[e] * ri) * (ej[e] * rj);
    const bool pred = (tid < 500) && (dot > 0.5f);
    unsigned long long m = __ballot(pred);
    if ((tid & 63) == 0) maskw[i * 8 + (tid >> 6)] = m;
}

// ---- transformer weight transposes into wT ----
// wT layout (floats): [0,256) wqT [256,512) wkT [512,768) wvT
//   [768,1024) woT [1024,1536) f1T [1536,2048) f2T [2048,2304) r1T
DEV void wt_fill(int tid, const float* __restrict__ wq, const float* __restrict__ wk,
                 const float* __restrict__ wv, const float* __restrict__ wo,
                 const float* __restrict__ fw1, const float* __restrict__ fw2,
                 const float* __restrict__ rw1, float* __restrict__ wT) {
    for (int t = tid; t < 2304; t += 512) {
        float v;
        if (t < 768) {
            const int base = t >> 8, loc = t & 255;
            const float* src = (base == 0) ? wq : (base == 1) ? wk : wv;
            v = src[(loc & 15) * 16 + (loc >> 4)];
        } else if (t < 1024) {
            const int loc = t - 768;
            v = wo[(loc & 15) * 16 + (loc >> 4)];
        } else if (t < 1536) {
            const int loc = t - 1024;
            v = fw1[(loc & 15) * 32 + (loc >> 4)];
        } else if (t < 2048) {
            const int loc = t - 1536;
            v = fw2[(loc & 31) * 16 + (loc >> 5)];
        } else {
            const int loc = t - 2048;
            v = rw1[(loc & 15) * 16 + (loc >> 4)];
        }
        wT[t] = v;
    }
}

// ---- GAT layer phase (per (graph b, head)); xh 4500f, h1 <=2000f, ssrc/sdst 500f ----
template <int C, int OUTS, bool PROJ, bool GELU_OUT>
DEV void gat_phase(float* __restrict__ xh, void* __restrict__ h1raw,
                   float* __restrict__ ssrc, float* __restrict__ sdst,
                   int b, int head, int tid,
                   const float* __restrict__ in, const float* __restrict__ pw,
                   const float* __restrict__ pb, const float* __restrict__ W,
                   const float* __restrict__ asrc, const float* __restrict__ adst,
                   const float* __restrict__ bias,
                   const unsigned long long* __restrict__ maskw,
                   float* __restrict__ out) {
    using Vec = std::conditional_t<C == 2, float2, float4>;
    Vec* h1 = (Vec*)h1raw;

    if (tid < 500) {
        if constexpr (PROJ) {
            const float* xr = in + ((size_t)b * 500 + tid) * 3;
            const float x0 = xr[0], x1 = xr[1], x2 = xr[2];
#pragma unroll
            for (int e = 0; e < 8; ++e)
                xh[tid * 9 + e] = x0 * pw[e] + x1 * pw[8 + e] + x2 * pw[16 + e] + pb[e];
        } else {
            const float4* xr = (const float4*)(in + ((size_t)b * 500 + tid) * 8);
            const float4 v0 = xr[0], v1 = xr[1];
            xh[tid * 9 + 0] = v0.x; xh[tid * 9 + 1] = v0.y;
            xh[tid * 9 + 2] = v0.z; xh[tid * 9 + 3] = v0.w;
            xh[tid * 9 + 4] = v1.x; xh[tid * 9 + 5] = v1.y;
            xh[tid * 9 + 6] = v1.z; xh[tid * 9 + 7] = v1.w;
        }
    }
    __syncthreads();

    if (tid < 500) {
        float xv[8];
#pragma unroll
        for (int e = 0; e < 8; ++e) xv[e] = xh[tid * 9 + e];
        float acc[C];
#pragma unroll
        for (int c = 0; c < C; ++c) acc[c] = 0.f;
#pragma unroll
        for (int e = 0; e < 8; ++e) {
            const float xe = xv[e];
#pragma unroll
            for (int c = 0; c < C; ++c) acc[c] += xe * W[(e * 4 + head) * C + c];
        }
        float ss = 0.f, sd = 0.f;
#pragma unroll
        for (int c = 0; c < C; ++c) {
            ss += acc[c] * asrc[head * C + c];
            sd += acc[c] * adst[head * C + c];
        }
        Vec hv;
        if constexpr (C == 2) { hv.x = acc[0]; hv.y = acc[1]; }
        else { hv.x = acc[0]; hv.y = acc[1]; hv.z = acc[2]; hv.w = acc[3]; }
        h1[tid] = hv;
        ssrc[tid] = ss;
        sdst[tid] = sd;
    }
    __syncthreads();

    if (tid < 500) {
        const int i = tid;
        const float dd = sdst[i];
        float num[C];
#pragma unroll
        for (int c = 0; c < C; ++c) num[c] = 0.f;
        float den = 0.f;
#pragma unroll 1
        for (int wi = 0; wi < 8; ++wi) {
            unsigned long long m = maskw[i * 8 + wi];
            while (m) {
                const int bit = __ffsll(m) - 1;
                m &= (m - 1);
                const int j = wi * 64 + bit;
                float e = dd + ssrc[j];
                e = (e > 0.f) ? e : 0.2f * e;
                const float w = __expf(e);
                den += w;
                const Vec hj = h1[j];
                if constexpr (C == 2) { num[0] += w * hj.x; num[1] += w * hj.y; }
                else { num[0] += w * hj.x; num[1] += w * hj.y;
                       num[2] += w * hj.z; num[3] += w * hj.w; }
            }
        }
        const float inv = 1.0f / den;  // diag self-loop guarantees den > 0
        float* orow = out + ((size_t)b * 500 + i) * OUTS + head * C;
#pragma unroll
        for (int c = 0; c < C; ++c) {
            float v = num[c] * inv + bias[head * C + c];
            if constexpr (GELU_OUT) v = gelu_exact(v);
            orow[c] = v;
        }
    }
}

// ---- transformer for one sequence r on 128 threads (2 waves), smem chunk S (3136 floats) ----
DEV void transformer_phase(float* __restrict__ S, int t, int r,
                           const float* __restrict__ tin, const float* __restrict__ wT,
                           const float* __restrict__ bq, const float* __restrict__ bk,
                           const float* __restrict__ bv, const float* __restrict__ bo,
                           const float* __restrict__ ln1g, const float* __restrict__ ln1b,
                           const float* __restrict__ ln2g, const float* __restrict__ ln2b,
                           const float* __restrict__ fb1, const float* __restrict__ fb2,
                           const float* __restrict__ rb1, const float* __restrict__ rw2,
                           const float* __restrict__ rb2, float* __restrict__ outp) {
    float (*t0)[16] = (float(*)[16])S;
    float (*qs)[16] = (float(*)[16])(S + 384);
    float (*ks)[16] = (float(*)[16])(S + 768);
    float (*vs)[16] = (float(*)[16])(S + 1152);
    float (*os)[16] = (float(*)[16])(S + 1536);
    float (*t1)[16] = (float(*)[16])(S + 1920);
    float (*hid)[32] = (float(*)[32])(S + 2304);
    float (*pooledp)[16] = (float(*)[16])(S + 3072);
    float* pooled = S + 3104;

    const int lane = t & 63;
    const int wave = t >> 6;          // 0..1
    const int d = t & 15;
    const int srow = (t >> 4) & 7;    // 0..7 across both waves
    const int f = t & 31;
    const int s4 = (t >> 5) & 3;

    const float4* row4 = (const float4*)(tin + (size_t)r * 384);
    float4* t04 = (float4*)&t0[0][0];
    if (t < 96) t04[t] = row4[t];
    const float4* wq4 = (const float4*)(wT + 0   + d * 16);
    const float4* wk4 = (const float4*)(wT + 256 + d * 16);
    const float4* wv4 = (const float4*)(wT + 512 + d * 16);
    const float4 q0 = wq4[0], q1 = wq4[1], q2 = wq4[2], q3 = wq4[3];
    const float4 k0 = wk4[0], k1 = wk4[1], k2 = wk4[2], k3 = wk4[3];
    const float4 v0 = wv4[0], v1 = wv4[1], v2 = wv4[2], v3 = wv4[3];
    const float bqv = bq[d], bkv = bk[d], bvv = bv[d];
    __syncthreads();

#pragma unroll
    for (int it = 0; it < 3; ++it) {
        const int s = it * 8 + srow;
        const float4 r0 = *(const float4*)&t0[s][0];
        const float4 r1 = *(const float4*)&t0[s][4];
        const float4 r2 = *(const float4*)&t0[s][8];
        const float4 r3 = *(const float4*)&t0[s][12];
        qs[s][d] = bqv + dot4(r0, q0) + dot4(r1, q1) + dot4(r2, q2) + dot4(r3, q3);
        ks[s][d] = bkv + dot4(r0, k0) + dot4(r1, k1) + dot4(r2, k2) + dot4(r3, k3);
        vs[s][d] = bvv + dot4(r0, v0) + dot4(r1, v1) + dot4(r2, v2) + dot4(r3, v3);
    }
    const float4* wo4 = (const float4*)(wT + 768 + d * 16);
    const float4 o0 = wo4[0], o1 = wo4[1], o2 = wo4[2], o3 = wo4[3];
    const float bov = bo[d];
    const float g1v = ln1g[d], be1v = ln1b[d];
    __syncthreads();

    // attention: head = wave, row = lane (lanes 0..23 of each wave)
    if (lane < 24) {
        const int h = wave, s = lane;
        const float4 qa = *(const float4*)&qs[s][h * 8];
        const float4 qb = *(const float4*)&qs[s][h * 8 + 4];
        float sc[24];
        float mx = -1e30f;
#pragma unroll
        for (int tt = 0; tt < 24; ++tt) {
            const float4 ka = *(const float4*)&ks[tt][h * 8];
            const float4 kb = *(const float4*)&ks[tt][h * 8 + 4];
            const float a = (dot4(qa, ka) + dot4(qb, kb)) * 0.35355339059327373f;
            sc[tt] = a;
            mx = fmaxf(mx, a);
        }
        float sum = 0.f;
#pragma unroll
        for (int tt = 0; tt < 24; ++tt) { sc[tt] = __expf(sc[tt] - mx); sum += sc[tt]; }
        const float inv = 1.0f / sum;
        float ax = 0.f, ay = 0.f, az = 0.f, aw = 0.f;
        float bx = 0.f, by = 0.f, bz = 0.f, bw = 0.f;
#pragma unroll
        for (int tt = 0; tt < 24; ++tt) {
            const float4 va = *(const float4*)&vs[tt][h * 8];
            const float4 vb = *(const float4*)&vs[tt][h * 8 + 4];
            const float w = sc[tt];
            ax += w * va.x; ay += w * va.y; az += w * va.z; aw += w * va.w;
            bx += w * vb.x; by += w * vb.y; bz += w * vb.z; bw += w * vb.w;
        }
        float4 ov0 = {ax * inv, ay * inv, az * inv, aw * inv};
        float4 ov1 = {bx * inv, by * inv, bz * inv, bw * inv};
        *(float4*)&os[s][h * 8] = ov0;
        *(float4*)&os[s][h * 8 + 4] = ov1;
    }
    const float4* f14 = (const float4*)(wT + 1024 + f * 16);
    const float4 fa0 = f14[0], fa1 = f14[1], fa2 = f14[2], fa3 = f14[3];
    const float fb1v = fb1[f];
    __syncthreads();

#pragma unroll
    for (int it = 0; it < 3; ++it) {
        const int s = it * 8 + srow;
        const float4 r0 = *(const float4*)&os[s][0];
        const float4 r1 = *(const float4*)&os[s][4];
        const float4 r2 = *(const float4*)&os[s][8];
        const float4 r3 = *(const float4*)&os[s][12];
        const float a = bov + dot4(r0, o0) + dot4(r1, o1) + dot4(r2, o2) + dot4(r3, o3);
        float xv = t0[s][d] + a;
        float sum = xv;
        sum += __shfl_xor(sum, 1); sum += __shfl_xor(sum, 2);
        sum += __shfl_xor(sum, 4); sum += __shfl_xor(sum, 8);
        const float mean = sum * 0.0625f;
        const float df = xv - mean;
        float v2 = df * df;
        v2 += __shfl_xor(v2, 1); v2 += __shfl_xor(v2, 2);
        v2 += __shfl_xor(v2, 4); v2 += __shfl_xor(v2, 8);
        t1[s][d] = df * rsqrtf(v2 * 0.0625f + 1e-3f) * g1v + be1v;
    }
    const float4* f24 = (const float4*)(wT + 1536 + d * 32);
    const float4 fb0_ = f24[0], fb1_ = f24[1], fb2_ = f24[2], fb3_ = f24[3];
    const float4 fb4_ = f24[4], fb5_ = f24[5], fb6_ = f24[6], fb7_ = f24[7];
    const float fb2v = fb2[d];
    const float g2v = ln2g[d], be2v = ln2b[d];
    __syncthreads();

#pragma unroll
    for (int it = 0; it < 6; ++it) {
        const int s = it * 4 + s4;
        const float4 r0 = *(const float4*)&t1[s][0];
        const float4 r1 = *(const float4*)&t1[s][4];
        const float4 r2 = *(const float4*)&t1[s][8];
        const float4 r3 = *(const float4*)&t1[s][12];
        const float a = fb1v + dot4(r0, fa0) + dot4(r1, fa1) + dot4(r2, fa2) + dot4(r3, fa3);
        hid[s][f] = gelu_exact(a);
    }
    const float4* r14 = (const float4*)(wT + 2048 + d * 16);
    const float4 ra0 = r14[0], ra1 = r14[1], ra2 = r14[2], ra3 = r14[3];
    const float rb1v = rb1[d], rw2v = rw2[d];
    __syncthreads();

    float pacc = 0.f;
#pragma unroll
    for (int it = 0; it < 3; ++it) {
        const int s = it * 8 + srow;
        const float4 h0 = *(const float4*)&hid[s][0];
        const float4 h1 = *(const float4*)&hid[s][4];
        const float4 h2 = *(const float4*)&hid[s][8];
        const float4 h3 = *(const float4*)&hid[s][12];
        const float4 h4 = *(const float4*)&hid[s][16];
        const float4 h5 = *(const float4*)&hid[s][20];
        const float4 h6 = *(const float4*)&hid[s][24];
        const float4 h7 = *(const float4*)&hid[s][28];
        const float a = fb2v +
            dot4(h0, fb0_) + dot4(h1, fb1_) + dot4(h2, fb2_) + dot4(h3, fb3_) +
            dot4(h4, fb4_) + dot4(h5, fb5_) + dot4(h6, fb6_) + dot4(h7, fb7_);
        float xv = t1[s][d] + a;
        float sum = xv;
        sum += __shfl_xor(sum, 1); sum += __shfl_xor(sum, 2);
        sum += __shfl_xor(sum, 4); sum += __shfl_xor(sum, 8);
        const float mean = sum * 0.0625f;
        const float df = xv - mean;
        float v2 = df * df;
        v2 += __shfl_xor(v2, 1); v2 += __shfl_xor(v2, 2);
        v2 += __shfl_xor(v2, 4); v2 += __shfl_xor(v2, 8);
        pacc += df * rsqrtf(v2 * 0.0625f + 1e-3f) * g2v + be2v;
    }
    pacc += __shfl_xor(pacc, 16);
    pacc += __shfl_xor(pacc, 32);
    if (lane < 16) pooledp[wave][lane] = pacc;
    __syncthreads();
    if (t < 16) pooled[t] = (pooledp[0][t] + pooledp[1][t]) * (1.0f / 24.0f);
    __syncthreads();

    float partial = 0.f;
    if (t < 16) {
        const float4 p0 = *(const float4*)&pooled[0];
        const float4 p1 = *(const float4*)&pooled[4];
        const float4 p2 = *(const float4*)&pooled[8];
        const float4 p3 = *(const float4*)&pooled[12];
        const float a = rb1v + dot4(p0, ra0) + dot4(p1, ra1) + dot4(p2, ra2) + dot4(p3, ra3);
        partial = gelu_exact(a) * rw2v;
    }
    partial += __shfl_xor(partial, 8);
    partial += __shfl_xor(partial, 4);
    partial += __shfl_xor(partial, 2);
    partial += __shfl_xor(partial, 1);
    if (t == 0) outp[r] = partial + rb2[0];
}

// ================= fused cooperative kernel =================

struct Params {
    const float *x, *emb, *proj_w, *proj_b;
    const float *g1_w, *g1_as, *g1_ad, *g1_b;
    const float *g2_w, *g2_as, *g2_ad, *g2_b;
    const float *wq, *bq, *wk, *bk, *wv, *bv, *wo, *bo;
    const float *ln1g, *ln1b, *ln2g, *ln2b;
    const float *fw1, *fb1, *fw2, *fb2;
    const float *rw1, *rb1, *rw2, *rb2;
    unsigned long long* maskw;
    float *wT, *h_g1, *t_buf, *outp;
};

// 500 blocks x 512 threads; __launch_bounds__(512,4) caps VGPR at 128 -> 2 blocks/CU
// -> 512 co-resident blocks >= 500 (cooperative-launch requirement).
__global__ __launch_bounds__(512, 4)
void fused_all(Params p) {
    __shared__ __align__(16) float smem[12544];  // 4 x 3136-float seq chunks / GAT scratch
    const int blk = blockIdx.x;
    const int tid = threadIdx.x;
    cg::grid_group grid = cg::this_grid();

    // P0: adjacency mask (+ weight transposes on block 0)
    mask_row(p.emb, p.maskw, blk, tid);
    if (blk == 0) wt_fill(tid, p.wq, p.wk, p.wv, p.wo, p.fw1, p.fw2, p.rw1, p.wT);
    __threadfence();
    grid.sync();

    // P1: GAT layer 1 (384 tiles)
    if (blk < 384) {
        float* xh = smem;                 // 4500 floats
        void* h1 = (void*)(smem + 4512);  // <=2000 floats, 16B-aligned
        float* ssrc = smem + 6512;
        float* sdst = smem + 7012;
        gat_phase<2, 8, true, true>(xh, h1, ssrc, sdst, blk >> 2, blk & 3, tid,
            p.x, p.proj_w, p.proj_b, p.g1_w, p.g1_as, p.g1_ad, p.g1_b,
            p.maskw, p.h_g1);
    }
    __threadfence();
    grid.sync();

    // P2: GAT layer 2
    if (blk < 384) {
        float* xh = smem;
        void* h1 = (void*)(smem + 4512);
        float* ssrc = smem + 6512;
        float* sdst = smem + 7012;
        gat_phase<4, 16, false, false>(xh, h1, ssrc, sdst, blk >> 2, blk & 3, tid,
            p.h_g1, nullptr, nullptr, p.g2_w, p.g2_as, p.g2_ad, p.g2_b,
            p.maskw, p.t_buf);
    }
    __threadfence();
    grid.sync();

    // P3: transformer, 4 sequences per block (500*4 = 2000)
    {
        const int lseq = tid >> 7;
        const int t = tid & 127;
        const int r = blk * 4 + lseq;
        transformer_phase(smem + lseq * 3136, t, r,
            p.t_buf, p.wT, p.bq, p.bk, p.bv, p.bo, p.ln1g, p.ln1b, p.ln2g, p.ln2b,
            p.fb1, p.fb2, p.rb1, p.rw2, p.rb2, p.outp);
    }
}

// ================= fallback standalone kernels =================

__global__ __launch_bounds__(512)
void mask_kernel(const float* __restrict__ emb, unsigned long long* __restrict__ maskw,
                 const float* __restrict__ wq, const float* __restrict__ wk,
                 const float* __restrict__ wv, const float* __restrict__ wo,
                 const float* __restrict__ fw1, const float* __restrict__ fw2,
                 const float* __restrict__ rw1, float* __restrict__ wT) {
    mask_row(emb, maskw, blockIdx.x, threadIdx.x);
    if (blockIdx.x == 0) wt_fill(threadIdx.x, wq, wk, wv, wo, fw1, fw2, rw1, wT);
}

template <int C, int OUTS, bool PROJ, bool GELU_OUT>
__global__ __launch_bounds__(512)
void gat_kernel(const float* __restrict__ in, const float* __restrict__ pw,
                const float* __restrict__ pb, const float* __restrict__ W,
                const float* __restrict__ asrc, const float* __restrict__ adst,
                const float* __restrict__ bias,
                const unsigned long long* __restrict__ maskw,
                float* __restrict__ out) {
    __shared__ __align__(16) float smem[7512];
    gat_phase<C, OUTS, PROJ, GELU_OUT>(smem, (void*)(smem + 4512), smem + 6512,
        smem + 7012, blockIdx.x >> 2, blockIdx.x & 3, threadIdx.x,
        in, pw, pb, W, asrc, adst, bias, maskw, out);
}

__global__ __launch_bounds__(128)
void transformer_kernel(const float* __restrict__ tin, const float* __restrict__ wT,
                        const float* __restrict__ bq, const float* __restrict__ bk,
                        const float* __restrict__ bv, const float* __restrict__ bo,
                        const float* __restrict__ ln1g, const float* __restrict__ ln1b,
                        const float* __restrict__ ln2g, const float* __restrict__ ln2b,
                        const float* __restrict__ fb1, const float* __restrict__ fb2,
                        const float* __restrict__ rb1, const float* __restrict__ rw2,
                        const float* __restrict__ rb2, float* __restrict__ outp) {
    __shared__ __align__(16) float S[3136];
    transformer_phase(S, threadIdx.x, blockIdx.x, tin, wT, bq, bk, bv, bo,
                      ln1g, ln1b, ln2g, ln2b, fb1, fb2, rb1, rw2, rb2, outp);
}

extern "C" void kernel_launch(void* const* d_in, const int* in_sizes, int n_in,
                              void* d_out, int out_size, void* d_ws, size_t ws_size,
                              hipStream_t stream) {
    const float* x      = (const float*)d_in[0];
    const float* emb    = (const float*)d_in[1];
    const float* proj_w = (const float*)d_in[2];
    const float* proj_b = (const float*)d_in[3];
    const float* g1_w   = (const float*)d_in[4];
    const float* g1_as  = (const float*)d_in[5];
    const float* g1_ad  = (const float*)d_in[6];
    const float* g1_b   = (const float*)d_in[7];
    const float* g2_w   = (const float*)d_in[8];
    const float* g2_as  = (const float*)d_in[9];
    const float* g2_ad  = (const float*)d_in[10];
    const float* g2_b   = (const float*)d_in[11];
    const float* wq = (const float*)d_in[12];
    const float* bq = (const float*)d_in[13];
    const float* wk = (const float*)d_in[14];
    const float* bk = (const float*)d_in[15];
    const float* wv = (const float*)d_in[16];
    const float* bv = (const float*)d_in[17];
    const float* wo = (const float*)d_in[18];
    const float* bo = (const float*)d_in[19];
    const float* ln1g = (const float*)d_in[20];
    const float* ln1b = (const float*)d_in[21];
    const float* ln2g = (const float*)d_in[22];
    const float* ln2b = (const float*)d_in[23];
    const float* fw1 = (const float*)d_in[24];
    const float* fb1 = (const float*)d_in[25];
    const float* fw2 = (const float*)d_in[26];
    const float* fb2 = (const float*)d_in[27];
    const float* rw1 = (const float*)d_in[28];
    const float* rb1 = (const float*)d_in[29];
    const float* rw2 = (const float*)d_in[30];
    const float* rb2 = (const float*)d_in[31];

    unsigned long long* maskw = (unsigned long long*)d_ws;       // 32000 B
    float* wT    = (float*)((char*)d_ws + 32768);                // 9216 B (pad 16384)
    float* h_g1  = (float*)((char*)d_ws + 49152);                // 1,536,000 B
    float* t_buf = (float*)((char*)d_ws + 49152 + 1536000);      // 3,072,000 B

    Params P;
    P.x = x; P.emb = emb; P.proj_w = proj_w; P.proj_b = proj_b;
    P.g1_w = g1_w; P.g1_as = g1_as; P.g1_ad = g1_ad; P.g1_b = g1_b;
    P.g2_w = g2_w; P.g2_as = g2_as; P.g2_ad = g2_ad; P.g2_b = g2_b;
    P.wq = wq; P.bq = bq; P.wk = wk; P.bk = bk; P.wv = wv; P.bv = bv;
    P.wo = wo; P.bo = bo; P.ln1g = ln1g; P.ln1b = ln1b; P.ln2g = ln2g; P.ln2b = ln2b;
    P.fw1 = fw1; P.fb1 = fb1; P.fw2 = fw2; P.fb2 = fb2;
    P.rw1 = rw1; P.rb1 = rb1; P.rw2 = rw2; P.rb2 = rb2;
    P.maskw = maskw; P.wT = wT; P.h_g1 = h_g1; P.t_buf = t_buf;
    P.outp = (float*)d_out;

    void* kargs[] = { (void*)&P };
    hipError_t err = hipLaunchCooperativeKernel(
        (const void*)fused_all, dim3(500), dim3(512), kargs, 0, stream);
    if (err != hipSuccess) {
        // fallback: original 4-dispatch pipeline
        mask_kernel<<<500, 512, 0, stream>>>(emb, maskw, wq, wk, wv, wo, fw1, fw2,
                                             rw1, wT);
        gat_kernel<2, 8, true, true><<<384, 512, 0, stream>>>(
            x, proj_w, proj_b, g1_w, g1_as, g1_ad, g1_b, maskw, h_g1);
        gat_kernel<4, 16, false, false><<<384, 512, 0, stream>>>(
            h_g1, nullptr, nullptr, g2_w, g2_as, g2_ad, g2_b, maskw, t_buf);
        transformer_kernel<<<2000, 128, 0, stream>>>(
            t_buf, wT, bq, bk, bv, bo, ln1g, ln1b, ln2g, ln2b,
            fb1, fb2, rb1, rw2, rb2, (float*)d_out);
    }
}

// Round 8
// 302.969 us; speedup vs baseline: 1.6371x; 1.6371x over previous
//
#include <hip/hip_runtime.h>
#include <hip/hip_cooperative_groups.h>
#include <math.h>
#include <type_traits>

namespace cg = cooperative_groups;

#define DEV __device__ __forceinline__

DEV float gelu_exact(float x) {
    return 0.5f * x * (1.0f + erff(x * 0.70710678118654752f));
}

DEV float dot4(const float4 a, const float4 b) {
    return a.x * b.x + a.y * b.y + a.z * b.z + a.w * b.w;
}

// ================= shared phase implementations =================

DEV void mask_row(const float* __restrict__ emb,
                  unsigned long long* __restrict__ maskw, int i, int tid) {
    float ei[8], ej[8];
    float si = 0.f, sj = 0.f;
#pragma unroll
    for (int e = 0; e < 8; ++e) { ei[e] = emb[i * 8 + e]; si += ei[e] * ei[e]; }
    const int jj = (tid < 500) ? tid : 0;
#pragma unroll
    for (int e = 0; e < 8; ++e) { ej[e] = emb[jj * 8 + e]; sj += ej[e] * ej[e]; }
    const float ri = 1.0f / sqrtf(si);
    const float rj = 1.0f / sqrtf(sj);
    float dot = 0.f;
#pragma unroll
    for (int e = 0; e < 8; ++e) dot += (ei[e] * ri) * (ej[e] * rj);
    const bool pred = (tid < 500) && (dot > 0.5f);
    unsigned long long m = __ballot(pred);
    if ((tid & 63) == 0) maskw[i * 8 + (tid >> 6)] = m;
}

// wT layout (floats): [0,256) wqT [256,512) wkT [512,768) wvT
//   [768,1024) woT [1024,1536) f1T [1536,2048) f2T [2048,2304) r1T
DEV void wt_fill(int tid, const float* __restrict__ wq, const float* __restrict__ wk,
                 const float* __restrict__ wv, const float* __restrict__ wo,
                 const float* __restrict__ fw1, const float* __restrict__ fw2,
                 const float* __restrict__ rw1, float* __restrict__ wT) {
    for (int t = tid; t < 2304; t += 512) {
        float v;
        if (t < 768) {
            const int base = t >> 8, loc = t & 255;
            const float* src = (base == 0) ? wq : (base == 1) ? wk : wv;
            v = src[(loc & 15) * 16 + (loc >> 4)];
        } else if (t < 1024) {
            const int loc = t - 768;
            v = wo[(loc & 15) * 16 + (loc >> 4)];
        } else if (t < 1536) {
            const int loc = t - 1024;
            v = fw1[(loc & 15) * 32 + (loc >> 4)];
        } else if (t < 2048) {
            const int loc = t - 1536;
            v = fw2[(loc & 31) * 16 + (loc >> 5)];
        } else {
            const int loc = t - 2048;
            v = rw1[(loc & 15) * 16 + (loc >> 4)];
        }
        wT[t] = v;
    }
}

// GAT layer: phases A/B over all 500 rows; phase C over rows [c_r0, c_r0+c_rows).
template <int C, int OUTS, bool PROJ, bool GELU_OUT>
DEV void gat_phase(float* __restrict__ xh, void* __restrict__ h1raw,
                   float* __restrict__ ssrc, float* __restrict__ sdst,
                   int b, int head, int c_r0, int c_rows, int tid,
                   const float* __restrict__ in, const float* __restrict__ pw,
                   const float* __restrict__ pb, const float* __restrict__ W,
                   const float* __restrict__ asrc, const float* __restrict__ adst,
                   const float* __restrict__ bias,
                   const unsigned long long* __restrict__ maskw,
                   float* __restrict__ out) {
    using Vec = std::conditional_t<C == 2, float2, float4>;
    Vec* h1 = (Vec*)h1raw;

    if (tid < 500) {
        if constexpr (PROJ) {
            const float* xr = in + ((size_t)b * 500 + tid) * 3;
            const float x0 = xr[0], x1 = xr[1], x2 = xr[2];
#pragma unroll
            for (int e = 0; e < 8; ++e)
                xh[tid * 9 + e] = x0 * pw[e] + x1 * pw[8 + e] + x2 * pw[16 + e] + pb[e];
        } else {
            const float4* xr = (const float4*)(in + ((size_t)b * 500 + tid) * 8);
            const float4 v0 = xr[0], v1 = xr[1];
            xh[tid * 9 + 0] = v0.x; xh[tid * 9 + 1] = v0.y;
            xh[tid * 9 + 2] = v0.z; xh[tid * 9 + 3] = v0.w;
            xh[tid * 9 + 4] = v1.x; xh[tid * 9 + 5] = v1.y;
            xh[tid * 9 + 6] = v1.z; xh[tid * 9 + 7] = v1.w;
        }
    }
    __syncthreads();

    if (tid < 500) {
        float xv[8];
#pragma unroll
        for (int e = 0; e < 8; ++e) xv[e] = xh[tid * 9 + e];
        float acc[C];
#pragma unroll
        for (int c = 0; c < C; ++c) acc[c] = 0.f;
#pragma unroll
        for (int e = 0; e < 8; ++e) {
            const float xe = xv[e];
#pragma unroll
            for (int c = 0; c < C; ++c) acc[c] += xe * W[(e * 4 + head) * C + c];
        }
        float ss = 0.f, sd = 0.f;
#pragma unroll
        for (int c = 0; c < C; ++c) {
            ss += acc[c] * asrc[head * C + c];
            sd += acc[c] * adst[head * C + c];
        }
        Vec hv;
        if constexpr (C == 2) { hv.x = acc[0]; hv.y = acc[1]; }
        else { hv.x = acc[0]; hv.y = acc[1]; hv.z = acc[2]; hv.w = acc[3]; }
        h1[tid] = hv;
        ssrc[tid] = ss;
        sdst[tid] = sd;
    }
    __syncthreads();

    if (tid < c_rows) {
        const int i = c_r0 + tid;
        const float dd = sdst[i];
        float num[C];
#pragma unroll
        for (int c = 0; c < C; ++c) num[c] = 0.f;
        float den = 0.f;
#pragma unroll 1
        for (int wi = 0; wi < 8; ++wi) {
            unsigned long long m = maskw[i * 8 + wi];
            while (m) {
                const int bit = __ffsll(m) - 1;
                m &= (m - 1);
                const int j = wi * 64 + bit;
                float e = dd + ssrc[j];
                e = (e > 0.f) ? e : 0.2f * e;
                const float w = __expf(e);
                den += w;
                const Vec hj = h1[j];
                if constexpr (C == 2) { num[0] += w * hj.x; num[1] += w * hj.y; }
                else { num[0] += w * hj.x; num[1] += w * hj.y;
                       num[2] += w * hj.z; num[3] += w * hj.w; }
            }
        }
        const float inv = 1.0f / den;  // diag self-loop guarantees den > 0
        float* orow = out + ((size_t)b * 500 + i) * OUTS + head * C;
#pragma unroll
        for (int c = 0; c < C; ++c) {
            float v = num[c] * inv + bias[head * C + c];
            if constexpr (GELU_OUT) v = gelu_exact(v);
            orow[c] = v;
        }
    }
}

// ---- transformer for one sequence on 64 threads; S = 1568-float LDS chunk ----
// Aliased layout (hazards separated by barriers or same-lane only):
//   t0@0(384)  qs/os@384(384)  ks/t1@768(384)  vs@1152(384)
//   hid@0(768, after t0+qs dead)  pooled@1152(16, after vs dead)
DEV void transformer_phase(float* __restrict__ S, int t, int r, bool active,
                           const float* __restrict__ tin, const float* __restrict__ wT,
                           const float* __restrict__ bq, const float* __restrict__ bk,
                           const float* __restrict__ bv, const float* __restrict__ bo,
                           const float* __restrict__ ln1g, const float* __restrict__ ln1b,
                           const float* __restrict__ ln2g, const float* __restrict__ ln2b,
                           const float* __restrict__ fb1, const float* __restrict__ fb2,
                           const float* __restrict__ rb1, const float* __restrict__ rw2,
                           const float* __restrict__ rb2, float* __restrict__ outp) {
    float (*t0)[16] = (float(*)[16])S;
    float (*qs)[16] = (float(*)[16])(S + 384);
    float (*os)[16] = (float(*)[16])(S + 384);   // alias qs
    float (*ks)[16] = (float(*)[16])(S + 768);
    float (*t1)[16] = (float(*)[16])(S + 768);   // alias ks
    float (*vs)[16] = (float(*)[16])(S + 1152);
    float (*hid)[32] = (float(*)[32])S;          // alias t0+qs
    float* pooled = S + 1152;                    // alias vs

    const int d = t & 15;
    const int srow = t >> 4;   // 0..3
    const int f = t & 31;
    const int s2 = t >> 5;     // 0..1

    const float4* row4 = (const float4*)(tin + (size_t)r * 384);
    float4* t04 = (float4*)&t0[0][0];
#pragma unroll
    for (int it = 0; it < 2; ++it) {
        const int idx = it * 64 + t;
        if (idx < 96) t04[idx] = row4[idx];
    }
    const float4* wq4 = (const float4*)(wT + 0   + d * 16);
    const float4* wk4 = (const float4*)(wT + 256 + d * 16);
    const float4* wv4 = (const float4*)(wT + 512 + d * 16);
    const float4 q0 = wq4[0], q1 = wq4[1], q2 = wq4[2], q3 = wq4[3];
    const float4 k0 = wk4[0], k1 = wk4[1], k2 = wk4[2], k3 = wk4[3];
    const float4 v0 = wv4[0], v1 = wv4[1], v2 = wv4[2], v3 = wv4[3];
    const float bqv = bq[d], bkv = bk[d], bvv = bv[d];
    __syncthreads();

    // QKV
#pragma unroll
    for (int it = 0; it < 6; ++it) {
        const int s = it * 4 + srow;
        const float4 r0 = *(const float4*)&t0[s][0];
        const float4 r1 = *(const float4*)&t0[s][4];
        const float4 r2 = *(const float4*)&t0[s][8];
        const float4 r3 = *(const float4*)&t0[s][12];
        qs[s][d] = bqv + dot4(r0, q0) + dot4(r1, q1) + dot4(r2, q2) + dot4(r3, q3);
        ks[s][d] = bkv + dot4(r0, k0) + dot4(r1, k1) + dot4(r2, k2) + dot4(r3, k3);
        vs[s][d] = bvv + dot4(r0, v0) + dot4(r1, v1) + dot4(r2, v2) + dot4(r3, v3);
    }
    const float4* wo4 = (const float4*)(wT + 768 + d * 16);
    const float4 o0 = wo4[0], o1 = wo4[1], o2 = wo4[2], o3 = wo4[3];
    const float bov = bo[d];
    const float g1v = ln1g[d], be1v = ln1b[d];
    __syncthreads();

    // attention: lane = h*24 + s for lane < 48; os[s][h*8..] written only by the
    // lane that read qs[s][h*8..] (same addresses, same lane) -> alias safe.
    if (t < 48) {
        const int h = t / 24, s = t % 24;
        const float4 qa = *(const float4*)&qs[s][h * 8];
        const float4 qb = *(const float4*)&qs[s][h * 8 + 4];
        float sc[24];
        float mx = -1e30f;
#pragma unroll
        for (int tt = 0; tt < 24; ++tt) {
            const float4 ka = *(const float4*)&ks[tt][h * 8];
            const float4 kb = *(const float4*)&ks[tt][h * 8 + 4];
            const float a = (dot4(qa, ka) + dot4(qb, kb)) * 0.35355339059327373f;
            sc[tt] = a;
            mx = fmaxf(mx, a);
        }
        float sum = 0.f;
#pragma unroll
        for (int tt = 0; tt < 24; ++tt) { sc[tt] = __expf(sc[tt] - mx); sum += sc[tt]; }
        const float inv = 1.0f / sum;
        float ax = 0.f, ay = 0.f, az = 0.f, aw = 0.f;
        float bx = 0.f, by = 0.f, bz = 0.f, bw = 0.f;
#pragma unroll
        for (int tt = 0; tt < 24; ++tt) {
            const float4 va = *(const float4*)&vs[tt][h * 8];
            const float4 vb = *(const float4*)&vs[tt][h * 8 + 4];
            const float w = sc[tt];
            ax += w * va.x; ay += w * va.y; az += w * va.z; aw += w * va.w;
            bx += w * vb.x; by += w * vb.y; bz += w * vb.z; bw += w * vb.w;
        }
        float4 ov0 = {ax * inv, ay * inv, az * inv, aw * inv};
        float4 ov1 = {bx * inv, by * inv, bz * inv, bw * inv};
        *(float4*)&os[s][h * 8] = ov0;
        *(float4*)&os[s][h * 8 + 4] = ov1;
    }
    const float4* f14 = (const float4*)(wT + 1024 + f * 16);
    const float4 fa0 = f14[0], fa1 = f14[1], fa2 = f14[2], fa3 = f14[3];
    const float fb1v = fb1[f];
    __syncthreads();

    // out-proj + residual + LN1 -> t1 (overwrites ks, dead after attention)
#pragma unroll
    for (int it = 0; it < 6; ++it) {
        const int s = it * 4 + srow;
        const float4 r0 = *(const float4*)&os[s][0];
        const float4 r1 = *(const float4*)&os[s][4];
        const float4 r2 = *(const float4*)&os[s][8];
        const float4 r3 = *(const float4*)&os[s][12];
        const float a = bov + dot4(r0, o0) + dot4(r1, o1) + dot4(r2, o2) + dot4(r3, o3);
        float xv = t0[s][d] + a;
        float sum = xv;
        sum += __shfl_xor(sum, 1); sum += __shfl_xor(sum, 2);
        sum += __shfl_xor(sum, 4); sum += __shfl_xor(sum, 8);
        const float mean = sum * 0.0625f;
        const float df = xv - mean;
        float v2 = df * df;
        v2 += __shfl_xor(v2, 1); v2 += __shfl_xor(v2, 2);
        v2 += __shfl_xor(v2, 4); v2 += __shfl_xor(v2, 8);
        t1[s][d] = df * rsqrtf(v2 * 0.0625f + 1e-3f) * g1v + be1v;
    }
    const float4* f24 = (const float4*)(wT + 1536 + d * 32);
    const float4 fb0_ = f24[0], fb1_ = f24[1], fb2_ = f24[2], fb3_ = f24[3];
    const float4 fb4_ = f24[4], fb5_ = f24[5], fb6_ = f24[6], fb7_ = f24[7];
    const float fb2v = fb2[d];
    const float g2v = ln2g[d], be2v = ln2b[d];
    __syncthreads();

    // FFN hidden -> hid (overwrites t0+qs, both dead now)
#pragma unroll
    for (int it = 0; it < 12; ++it) {
        const int s = it * 2 + s2;
        const float4 r0 = *(const float4*)&t1[s][0];
        const float4 r1 = *(const float4*)&t1[s][4];
        const float4 r2 = *(const float4*)&t1[s][8];
        const float4 r3 = *(const float4*)&t1[s][12];
        const float a = fb1v + dot4(r0, fa0) + dot4(r1, fa1) + dot4(r2, fa2) + dot4(r3, fa3);
        hid[s][f] = gelu_exact(a);
    }
    const float4* r14 = (const float4*)(wT + 2048 + d * 16);
    const float4 ra0 = r14[0], ra1 = r14[1], ra2 = r14[2], ra3 = r14[3];
    const float rb1v = rb1[d], rw2v = rw2[d];
    __syncthreads();

    // FFN out + residual + LN2 + pool partial
    float pacc = 0.f;
#pragma unroll
    for (int it = 0; it < 6; ++it) {
        const int s = it * 4 + srow;
        const float4 h0 = *(const float4*)&hid[s][0];
        const float4 h1 = *(const float4*)&hid[s][4];
        const float4 h2 = *(const float4*)&hid[s][8];
        const float4 h3 = *(const float4*)&hid[s][12];
        const float4 h4 = *(const float4*)&hid[s][16];
        const float4 h5 = *(const float4*)&hid[s][20];
        const float4 h6 = *(const float4*)&hid[s][24];
        const float4 h7 = *(const float4*)&hid[s][28];
        const float a = fb2v +
            dot4(h0, fb0_) + dot4(h1, fb1_) + dot4(h2, fb2_) + dot4(h3, fb3_) +
            dot4(h4, fb4_) + dot4(h5, fb5_) + dot4(h6, fb6_) + dot4(h7, fb7_);
        float xv = t1[s][d] + a;
        float sum = xv;
        sum += __shfl_xor(sum, 1); sum += __shfl_xor(sum, 2);
        sum += __shfl_xor(sum, 4); sum += __shfl_xor(sum, 8);
        const float mean = sum * 0.0625f;
        const float df = xv - mean;
        float v2 = df * df;
        v2 += __shfl_xor(v2, 1); v2 += __shfl_xor(v2, 2);
        v2 += __shfl_xor(v2, 4); v2 += __shfl_xor(v2, 8);
        pacc += df * rsqrtf(v2 * 0.0625f + 1e-3f) * g2v + be2v;
    }
    pacc += __shfl_xor(pacc, 16);
    pacc += __shfl_xor(pacc, 32);
    if (t < 16) pooled[t] = pacc * (1.0f / 24.0f);  // vs dead
    __syncthreads();

    float partial = 0.f;
    if (t < 16) {
        const float4 p0 = *(const float4*)&pooled[0];
        const float4 p1 = *(const float4*)&pooled[4];
        const float4 p2 = *(const float4*)&pooled[8];
        const float4 p3 = *(const float4*)&pooled[12];
        const float a = rb1v + dot4(p0, ra0) + dot4(p1, ra1) + dot4(p2, ra2) + dot4(p3, ra3);
        partial = gelu_exact(a) * rw2v;
    }
    partial += __shfl_xor(partial, 8);
    partial += __shfl_xor(partial, 4);
    partial += __shfl_xor(partial, 2);
    partial += __shfl_xor(partial, 1);
    if (t == 0 && active) outp[r] = partial + rb2[0];
}

// ================= fused cooperative kernel =================

struct Params {
    const float *x, *emb, *proj_w, *proj_b;
    const float *g1_w, *g1_as, *g1_ad, *g1_b;
    const float *g2_w, *g2_as, *g2_ad, *g2_b;
    const float *wq, *bq, *wk, *bk, *wv, *bv, *wo, *bo;
    const float *ln1g, *ln1b, *ln2g, *ln2b;
    const float *fw1, *fb1, *fw2, *fb2;
    const float *rw1, *rb1, *rw2, *rb2;
    unsigned long long* maskw;
    float *wT, *h_g1, *t_buf, *outp;
};

// grid = 256 blocks x 512 threads; __launch_bounds__(512,2) -> VGPR cap 256
// (R6's (512,4) forced VGPR=64 and ~13MB scratch spill -> 485us).
// LDS 50,176 B -> >=1 block/CU guaranteed, 256 co-resident blocks.
__global__ __launch_bounds__(512, 2)
void fused_all(Params p) {
    __shared__ __align__(16) float smem[12544];  // 8 x 1568-float seq chunks / GAT scratch
    const int blk = blockIdx.x;
    const int tid = threadIdx.x;
    cg::grid_group grid = cg::this_grid();

    // P0: adjacency mask rows (500 over 256 blocks) + weight transposes
    for (int i = blk; i < 500; i += 256) mask_row(p.emb, p.maskw, i, tid);
    if (blk == 0) wt_fill(tid, p.wq, p.wk, p.wv, p.wo, p.fw1, p.fw2, p.rw1, p.wT);
    __threadfence();
    grid.sync();

    // P1: GAT layer 1 — 768 half-tiles, exactly 3 per block
    for (int ht = blk * 3; ht < blk * 3 + 3; ++ht) {
        const int tile = ht >> 1;
        gat_phase<2, 8, true, true>(smem, (void*)(smem + 4512), smem + 6512,
            smem + 7012, tile >> 2, tile & 3, (ht & 1) * 250, 250, tid,
            p.x, p.proj_w, p.proj_b, p.g1_w, p.g1_as, p.g1_ad, p.g1_b,
            p.maskw, p.h_g1);
        __syncthreads();
    }
    __threadfence();
    grid.sync();

    // P2: GAT layer 2 — same decomposition
    for (int ht = blk * 3; ht < blk * 3 + 3; ++ht) {
        const int tile = ht >> 1;
        gat_phase<4, 16, false, false>(smem, (void*)(smem + 4512), smem + 6512,
            smem + 7012, tile >> 2, tile & 3, (ht & 1) * 250, 250, tid,
            p.h_g1, nullptr, nullptr, p.g2_w, p.g2_as, p.g2_ad, p.g2_b,
            p.maskw, p.t_buf);
        __syncthreads();
    }
    __threadfence();
    grid.sync();

    // P3: transformer — 8 x 64-thread groups per block (2048 slots >= 2000)
    {
        const int g = tid >> 6;
        const int t = tid & 63;
        const int r = blk * 8 + g;
        const bool active = (r < 2000);
        transformer_phase(smem + g * 1568, t, active ? r : 0, active,
            p.t_buf, p.wT, p.bq, p.bk, p.bv, p.bo, p.ln1g, p.ln1b, p.ln2g, p.ln2b,
            p.fb1, p.fb2, p.rb1, p.rw2, p.rb2, p.outp);
    }
}

// ================= fallback standalone kernels =================

__global__ __launch_bounds__(512)
void mask_kernel(const float* __restrict__ emb, unsigned long long* __restrict__ maskw,
                 const float* __restrict__ wq, const float* __restrict__ wk,
                 const float* __restrict__ wv, const float* __restrict__ wo,
                 const float* __restrict__ fw1, const float* __restrict__ fw2,
                 const float* __restrict__ rw1, float* __restrict__ wT) {
    mask_row(emb, maskw, blockIdx.x, threadIdx.x);
    if (blockIdx.x == 0) wt_fill(threadIdx.x, wq, wk, wv, wo, fw1, fw2, rw1, wT);
}

template <int C, int OUTS, bool PROJ, bool GELU_OUT>
__global__ __launch_bounds__(512)
void gat_kernel(const float* __restrict__ in, const float* __restrict__ pw,
                const float* __restrict__ pb, const float* __restrict__ W,
                const float* __restrict__ asrc, const float* __restrict__ adst,
                const float* __restrict__ bias,
                const unsigned long long* __restrict__ maskw,
                float* __restrict__ out) {
    __shared__ __align__(16) float smem[7512];
    gat_phase<C, OUTS, PROJ, GELU_OUT>(smem, (void*)(smem + 4512), smem + 6512,
        smem + 7012, blockIdx.x >> 2, blockIdx.x & 3, 0, 500, threadIdx.x,
        in, pw, pb, W, asrc, adst, bias, maskw, out);
}

__global__ __launch_bounds__(64)
void transformer_kernel(const float* __restrict__ tin, const float* __restrict__ wT,
                        const float* __restrict__ bq, const float* __restrict__ bk,
                        const float* __restrict__ bv, const float* __restrict__ bo,
                        const float* __restrict__ ln1g, const float* __restrict__ ln1b,
                        const float* __restrict__ ln2g, const float* __restrict__ ln2b,
                        const float* __restrict__ fb1, const float* __restrict__ fb2,
                        const float* __restrict__ rb1, const float* __restrict__ rw2,
                        const float* __restrict__ rb2, float* __restrict__ outp) {
    __shared__ __align__(16) float S[1568];
    transformer_phase(S, threadIdx.x, blockIdx.x, true, tin, wT, bq, bk, bv, bo,
                      ln1g, ln1b, ln2g, ln2b, fb1, fb2, rb1, rw2, rb2, outp);
}

extern "C" void kernel_launch(void* const* d_in, const int* in_sizes, int n_in,
                              void* d_out, int out_size, void* d_ws, size_t ws_size,
                              hipStream_t stream) {
    const float* x      = (const float*)d_in[0];
    const float* emb    = (const float*)d_in[1];
    const float* proj_w = (const float*)d_in[2];
    const float* proj_b = (const float*)d_in[3];
    const float* g1_w   = (const float*)d_in[4];
    const float* g1_as  = (const float*)d_in[5];
    const float* g1_ad  = (const float*)d_in[6];
    const float* g1_b   = (const float*)d_in[7];
    const float* g2_w   = (const float*)d_in[8];
    const float* g2_as  = (const float*)d_in[9];
    const float* g2_ad  = (const float*)d_in[10];
    const float* g2_b   = (const float*)d_in[11];
    const float* wq = (const float*)d_in[12];
    const float* bq = (const float*)d_in[13];
    const float* wk = (const float*)d_in[14];
    const float* bk = (const float*)d_in[15];
    const float* wv = (const float*)d_in[16];
    const float* bv = (const float*)d_in[17];
    const float* wo = (const float*)d_in[18];
    const float* bo = (const float*)d_in[19];
    const float* ln1g = (const float*)d_in[20];
    const float* ln1b = (const float*)d_in[21];
    const float* ln2g = (const float*)d_in[22];
    const float* ln2b = (const float*)d_in[23];
    const float* fw1 = (const float*)d_in[24];
    const float* fb1 = (const float*)d_in[25];
    const float* fw2 = (const float*)d_in[26];
    const float* fb2 = (const float*)d_in[27];
    const float* rw1 = (const float*)d_in[28];
    const float* rb1 = (const float*)d_in[29];
    const float* rw2 = (const float*)d_in[30];
    const float* rb2 = (const float*)d_in[31];

    unsigned long long* maskw = (unsigned long long*)d_ws;       // 32000 B
    float* wT    = (float*)((char*)d_ws + 32768);                // 9216 B (pad 16384)
    float* h_g1  = (float*)((char*)d_ws + 49152);                // 1,536,000 B
    float* t_buf = (float*)((char*)d_ws + 49152 + 1536000);      // 3,072,000 B

    Params P;
    P.x = x; P.emb = emb; P.proj_w = proj_w; P.proj_b = proj_b;
    P.g1_w = g1_w; P.g1_as = g1_as; P.g1_ad = g1_ad; P.g1_b = g1_b;
    P.g2_w = g2_w; P.g2_as = g2_as; P.g2_ad = g2_ad; P.g2_b = g2_b;
    P.wq = wq; P.bq = bq; P.wk = wk; P.bk = bk; P.wv = wv; P.bv = bv;
    P.wo = wo; P.bo = bo; P.ln1g = ln1g; P.ln1b = ln1b; P.ln2g = ln2g; P.ln2b = ln2b;
    P.fw1 = fw1; P.fb1 = fb1; P.fw2 = fw2; P.fb2 = fb2;
    P.rw1 = rw1; P.rb1 = rb1; P.rw2 = rw2; P.rb2 = rb2;
    P.maskw = maskw; P.wT = wT; P.h_g1 = h_g1; P.t_buf = t_buf;
    P.outp = (float*)d_out;

    void* kargs[] = { (void*)&P };
    hipError_t err = hipLaunchCooperativeKernel(
        (const void*)fused_all, dim3(256), dim3(512), kargs, 0, stream);
    if (err != hipSuccess) {
        // fallback: 4-dispatch pipeline
        mask_kernel<<<500, 512, 0, stream>>>(emb, maskw, wq, wk, wv, wo, fw1, fw2,
                                             rw1, wT);
        gat_kernel<2, 8, true, true><<<384, 512, 0, stream>>>(
            x, proj_w, proj_b, g1_w, g1_as, g1_ad, g1_b, maskw, h_g1);
        gat_kernel<4, 16, false, false><<<384, 512, 0, stream>>>(
            h_g1, nullptr, nullptr, g2_w, g2_as, g2_ad, g2_b, maskw, t_buf);
        transformer_kernel<<<2000, 64, 0, stream>>>(
            t_buf, wT, bq, bk, bv, bo, ln1g, ln1b, ln2g, ln2b,
            fb1, fb2, rb1, rw2, rb2, (float*)d_out);
    }
}

// Round 9
// 49.682 us; speedup vs baseline: 9.9832x; 6.0982x over previous
//
#include <hip/hip_runtime.h>
#include <math.h>
#include <type_traits>

#define DEV __device__ __forceinline__

DEV float gelu_exact(float x) {
    return 0.5f * x * (1.0f + erff(x * 0.70710678118654752f));
}

// ---------------- K1: adjacency -> CSR neighbor lists ----------------
// grid = 500 blocks (row i), 512 threads (col j). Output: nbr[i*128+k] (u16,
// ascending j) and deg[i]. Self-loop (diag=1>0.5) guarantees deg>=1.
__global__ __launch_bounds__(512)
void mask_kernel(const float* __restrict__ emb,
                 unsigned short* __restrict__ nbr,
                 int* __restrict__ deg) {
    const int i = blockIdx.x;
    const int j = threadIdx.x;
    float ei[8], ej[8];
    float si = 0.f, sj = 0.f;
#pragma unroll
    for (int e = 0; e < 8; ++e) { ei[e] = emb[i * 8 + e]; si += ei[e] * ei[e]; }
    const int jj = (j < 500) ? j : 0;
#pragma unroll
    for (int e = 0; e < 8; ++e) { ej[e] = emb[jj * 8 + e]; sj += ej[e] * ej[e]; }
    const float ri = 1.0f / sqrtf(si);
    const float rj = 1.0f / sqrtf(sj);
    float dot = 0.f;
#pragma unroll
    for (int e = 0; e < 8; ++e) dot += (ei[e] * ri) * (ej[e] * rj);
    const bool pred = (j < 500) && (dot > 0.5f);
    const unsigned long long m = __ballot(pred);

    __shared__ unsigned wcnt[8];
    const int wave = j >> 6, lane = j & 63;
    if (lane == 0) wcnt[wave] = (unsigned)__popcll(m);
    __syncthreads();
    unsigned off = 0;
    for (int w = 0; w < wave; ++w) off += wcnt[w];
    if (pred) {
        const unsigned pos = off + (unsigned)__popcll(m & ((1ull << lane) - 1ull));
        if (pos < 128) nbr[i * 128 + pos] = (unsigned short)j;
    }
    if (j == 0) {
        unsigned t = 0;
        for (int w = 0; w < 8; ++w) t += wcnt[w];
        deg[i] = (int)(t > 128u ? 128u : t);
    }
}

// ---------------- K2/K3: per-layer GAT ----------------
// grid = 96 graphs * 4 heads = 384 blocks, 512 threads (1 row/thread).
// Aggregation: fixed-trip CSR loop, 4-way unrolled (8 independent LDS reads
// + 4 independent exps per iter) instead of the serial bit-scan chain.
template <int C, int OUTS, bool PROJ, bool GELU_OUT>
__global__ __launch_bounds__(512)
void gat_kernel(const float* __restrict__ in,
                const float* __restrict__ pw,   // [3,8] (PROJ only)
                const float* __restrict__ pb,   // [8]
                const float* __restrict__ W,    // [8,4,C]
                const float* __restrict__ asrc, // [4,C]
                const float* __restrict__ adst, // [4,C]
                const float* __restrict__ bias, // [4*C]
                const unsigned short* __restrict__ nbr, // [500][128]
                const int* __restrict__ deg,            // [500]
                float* __restrict__ out) {      // [96,500,OUTS]
    using Vec = std::conditional_t<C == 2, float2, float4>;
    const int b = blockIdx.x >> 2;
    const int head = blockIdx.x & 3;
    const int tid = threadIdx.x;
    __shared__ float xh[500 * 9];   // stride 9 (odd)
    __shared__ Vec h1[500];
    __shared__ float ssrc[500];
    __shared__ float sdst[500];

    // A: stage input (optionally fused dense proj 3->8)
    if (tid < 500) {
        if constexpr (PROJ) {
            const float* xr = in + ((size_t)b * 500 + tid) * 3;
            const float x0 = xr[0], x1 = xr[1], x2 = xr[2];
#pragma unroll
            for (int e = 0; e < 8; ++e)
                xh[tid * 9 + e] = x0 * pw[e] + x1 * pw[8 + e] + x2 * pw[16 + e] + pb[e];
        } else {
            const float4* xr = (const float4*)(in + ((size_t)b * 500 + tid) * 8);
            const float4 v0 = xr[0], v1 = xr[1];
            xh[tid * 9 + 0] = v0.x; xh[tid * 9 + 1] = v0.y;
            xh[tid * 9 + 2] = v0.z; xh[tid * 9 + 3] = v0.w;
            xh[tid * 9 + 4] = v1.x; xh[tid * 9 + 5] = v1.y;
            xh[tid * 9 + 6] = v1.z; xh[tid * 9 + 7] = v1.w;
        }
    }
    __syncthreads();

    // B: per-head projection + attention logits
    if (tid < 500) {
        float xv[8];
#pragma unroll
        for (int e = 0; e < 8; ++e) xv[e] = xh[tid * 9 + e];
        float acc[C];
#pragma unroll
        for (int c = 0; c < C; ++c) acc[c] = 0.f;
#pragma unroll
        for (int e = 0; e < 8; ++e) {
            const float xe = xv[e];
#pragma unroll
            for (int c = 0; c < C; ++c) acc[c] += xe * W[(e * 4 + head) * C + c];
        }
        float ss = 0.f, sd = 0.f;
#pragma unroll
        for (int c = 0; c < C; ++c) {
            ss += acc[c] * asrc[head * C + c];
            sd += acc[c] * adst[head * C + c];
        }
        Vec hv;
        if constexpr (C == 2) { hv.x = acc[0]; hv.y = acc[1]; }
        else { hv.x = acc[0]; hv.y = acc[1]; hv.z = acc[2]; hv.w = acc[3]; }
        h1[tid] = hv;
        ssrc[tid] = ss;
        sdst[tid] = sd;
    }
    __syncthreads();

    // C: masked rank-1 softmax aggregation over CSR neighbors
    if (tid < 500) {
        const int i = tid;
        const float dd = sdst[i];
        const int dg = deg[i];
        const unsigned short* nb = nbr + i * 128;
        float num[C];
#pragma unroll
        for (int c = 0; c < C; ++c) num[c] = 0.f;
        float den = 0.f;
        int k = 0;
        for (; k + 4 <= dg; k += 4) {
            const ushort4 j4 = *(const ushort4*)(nb + k);
            float e0 = dd + ssrc[j4.x]; e0 = (e0 > 0.f) ? e0 : 0.2f * e0;
            float e1 = dd + ssrc[j4.y]; e1 = (e1 > 0.f) ? e1 : 0.2f * e1;
            float e2 = dd + ssrc[j4.z]; e2 = (e2 > 0.f) ? e2 : 0.2f * e2;
            float e3 = dd + ssrc[j4.w]; e3 = (e3 > 0.f) ? e3 : 0.2f * e3;
            const float w0 = __expf(e0), w1 = __expf(e1);
            const float w2 = __expf(e2), w3 = __expf(e3);
            const Vec ha = h1[j4.x], hb = h1[j4.y], hc = h1[j4.z], hd = h1[j4.w];
            den += (w0 + w1) + (w2 + w3);
            if constexpr (C == 2) {
                num[0] += (w0 * ha.x + w1 * hb.x) + (w2 * hc.x + w3 * hd.x);
                num[1] += (w0 * ha.y + w1 * hb.y) + (w2 * hc.y + w3 * hd.y);
            } else {
                num[0] += (w0 * ha.x + w1 * hb.x) + (w2 * hc.x + w3 * hd.x);
                num[1] += (w0 * ha.y + w1 * hb.y) + (w2 * hc.y + w3 * hd.y);
                num[2] += (w0 * ha.z + w1 * hb.z) + (w2 * hc.z + w3 * hd.z);
                num[3] += (w0 * ha.w + w1 * hb.w) + (w2 * hc.w + w3 * hd.w);
            }
        }
        for (; k < dg; ++k) {
            const int j = nb[k];
            float e = dd + ssrc[j];
            e = (e > 0.f) ? e : 0.2f * e;
            const float w = __expf(e);
            den += w;
            const Vec hj = h1[j];
            if constexpr (C == 2) { num[0] += w * hj.x; num[1] += w * hj.y; }
            else { num[0] += w * hj.x; num[1] += w * hj.y;
                   num[2] += w * hj.z; num[3] += w * hj.w; }
        }
        const float inv = 1.0f / den;  // self-loop guarantees den > 0
        float* orow = out + ((size_t)b * 500 + i) * OUTS + head * C;
#pragma unroll
        for (int c = 0; c < C; ++c) {
            float v = num[c] * inv + bias[head * C + c];
            if constexpr (GELU_OUT) v = gelu_exact(v);
            orow[c] = v;
        }
    }
}

// ---------------- K4: transformer + pool + regressor (byte-identical to R3) ----
__global__ __launch_bounds__(64)
void transformer_kernel(const float* __restrict__ tin,  // [2000,24,16]
                        const float* __restrict__ wq, const float* __restrict__ bq,
                        const float* __restrict__ wk, const float* __restrict__ bk,
                        const float* __restrict__ wv, const float* __restrict__ bv,
                        const float* __restrict__ wo, const float* __restrict__ bo,
                        const float* __restrict__ ln1g, const float* __restrict__ ln1b,
                        const float* __restrict__ ln2g, const float* __restrict__ ln2b,
                        const float* __restrict__ fw1, const float* __restrict__ fb1,
                        const float* __restrict__ fw2, const float* __restrict__ fb2,
                        const float* __restrict__ rw1, const float* __restrict__ rb1,
                        const float* __restrict__ rw2, const float* __restrict__ rb2,
                        float* __restrict__ outp) {
    const int r = blockIdx.x;
    const int lane = threadIdx.x;
    const int d = lane & 15;
    const int srow = lane >> 4;   // 0..3
    const int f = lane & 31;      // FFN1 column
    const int s2 = lane >> 5;     // 0..1
    __shared__ float t0[24][16], qs[24][16], ks[24][16], vs[24][16];
    __shared__ float os[24][16], t1[24][16], hid[24][32], pooled[16];

    const float4* row4 = (const float4*)(tin + (size_t)r * 384);
    float4* t04 = (float4*)&t0[0][0];
    for (int idx = lane; idx < 96; idx += 64) t04[idx] = row4[idx];
    float wqc[16], wkc[16], wvc[16];
#pragma unroll
    for (int e = 0; e < 16; ++e) {
        wqc[e] = wq[e * 16 + d];
        wkc[e] = wk[e * 16 + d];
        wvc[e] = wv[e * 16 + d];
    }
    const float bqv = bq[d], bkv = bk[d], bvv = bv[d];
    __syncthreads();

    // QKV
#pragma unroll
    for (int it = 0; it < 6; ++it) {
        const int s = it * 4 + srow;
        const float4 r0 = *(const float4*)&t0[s][0];
        const float4 r1 = *(const float4*)&t0[s][4];
        const float4 r2 = *(const float4*)&t0[s][8];
        const float4 r3 = *(const float4*)&t0[s][12];
        const float te[16] = {r0.x, r0.y, r0.z, r0.w, r1.x, r1.y, r1.z, r1.w,
                              r2.x, r2.y, r2.z, r2.w, r3.x, r3.y, r3.z, r3.w};
        float aq = bqv, ak = bkv, av = bvv;
#pragma unroll
        for (int e = 0; e < 16; ++e) {
            aq += te[e] * wqc[e];
            ak += te[e] * wkc[e];
            av += te[e] * wvc[e];
        }
        qs[s][d] = aq; ks[s][d] = ak; vs[s][d] = av;
    }
    __syncthreads();

    // attention: lane = h*24 + s for lane < 48
    if (lane < 48) {
        const int h = lane / 24, s = lane % 24;
        const float4 q0 = *(const float4*)&qs[s][h * 8];
        const float4 q1 = *(const float4*)&qs[s][h * 8 + 4];
        float sc[24];
        float mx = -1e30f;
#pragma unroll
        for (int t = 0; t < 24; ++t) {
            const float4 k0 = *(const float4*)&ks[t][h * 8];
            const float4 k1 = *(const float4*)&ks[t][h * 8 + 4];
            float a = q0.x * k0.x + q0.y * k0.y + q0.z * k0.z + q0.w * k0.w +
                      q1.x * k1.x + q1.y * k1.y + q1.z * k1.z + q1.w * k1.w;
            a *= 0.35355339059327373f;  // 1/sqrt(8)
            sc[t] = a;
            mx = fmaxf(mx, a);
        }
        float sum = 0.f;
#pragma unroll
        for (int t = 0; t < 24; ++t) { sc[t] = __expf(sc[t] - mx); sum += sc[t]; }
        const float inv = 1.0f / sum;
        float o0x = 0.f, o0y = 0.f, o0z = 0.f, o0w = 0.f;
        float o1x = 0.f, o1y = 0.f, o1z = 0.f, o1w = 0.f;
#pragma unroll
        for (int t = 0; t < 24; ++t) {
            const float4 v0 = *(const float4*)&vs[t][h * 8];
            const float4 v1 = *(const float4*)&vs[t][h * 8 + 4];
            const float w = sc[t];
            o0x += w * v0.x; o0y += w * v0.y; o0z += w * v0.z; o0w += w * v0.w;
            o1x += w * v1.x; o1y += w * v1.y; o1z += w * v1.z; o1w += w * v1.w;
        }
        float4 ov0 = {o0x * inv, o0y * inv, o0z * inv, o0w * inv};
        float4 ov1 = {o1x * inv, o1y * inv, o1z * inv, o1w * inv};
        *(float4*)&os[s][h * 8] = ov0;
        *(float4*)&os[s][h * 8 + 4] = ov1;
    }
    float woc[16];
#pragma unroll
    for (int hd = 0; hd < 16; ++hd) woc[hd] = wo[hd * 16 + d];
    const float bov = bo[d];
    const float g1v = ln1g[d], be1v = ln1b[d];
    __syncthreads();

    // out-proj + residual + LN1
#pragma unroll
    for (int it = 0; it < 6; ++it) {
        const int s = it * 4 + srow;
        const float4 r0 = *(const float4*)&os[s][0];
        const float4 r1 = *(const float4*)&os[s][4];
        const float4 r2 = *(const float4*)&os[s][8];
        const float4 r3 = *(const float4*)&os[s][12];
        const float oe[16] = {r0.x, r0.y, r0.z, r0.w, r1.x, r1.y, r1.z, r1.w,
                              r2.x, r2.y, r2.z, r2.w, r3.x, r3.y, r3.z, r3.w};
        float a = bov;
#pragma unroll
        for (int hd = 0; hd < 16; ++hd) a += oe[hd] * woc[hd];
        float xv = t0[s][d] + a;
        float sum = xv;
        sum += __shfl_xor(sum, 1); sum += __shfl_xor(sum, 2);
        sum += __shfl_xor(sum, 4); sum += __shfl_xor(sum, 8);
        const float mean = sum * 0.0625f;
        const float df = xv - mean;
        float v2 = df * df;
        v2 += __shfl_xor(v2, 1); v2 += __shfl_xor(v2, 2);
        v2 += __shfl_xor(v2, 4); v2 += __shfl_xor(v2, 8);
        const float var = v2 * 0.0625f;
        t1[s][d] = df * rsqrtf(var + 1e-3f) * g1v + be1v;
    }
    float f1c[16];
#pragma unroll
    for (int e = 0; e < 16; ++e) f1c[e] = fw1[e * 32 + f];
    const float fb1v = fb1[f];
    __syncthreads();

    // FFN hidden [24][32]
#pragma unroll
    for (int it = 0; it < 12; ++it) {
        const int s = it * 2 + s2;
        const float4 r0 = *(const float4*)&t1[s][0];
        const float4 r1 = *(const float4*)&t1[s][4];
        const float4 r2 = *(const float4*)&t1[s][8];
        const float4 r3 = *(const float4*)&t1[s][12];
        const float te[16] = {r0.x, r0.y, r0.z, r0.w, r1.x, r1.y, r1.z, r1.w,
                              r2.x, r2.y, r2.z, r2.w, r3.x, r3.y, r3.z, r3.w};
        float a = fb1v;
#pragma unroll
        for (int e = 0; e < 16; ++e) a += te[e] * f1c[e];
        hid[s][f] = gelu_exact(a);
    }
    float f2c[32];
#pragma unroll
    for (int ff = 0; ff < 32; ++ff) f2c[ff] = fw2[ff * 16 + d];
    const float fb2v = fb2[d];
    const float g2v = ln2g[d], be2v = ln2b[d];
    __syncthreads();

    // FFN out + residual + LN2 + fused mean-pool accumulate
    float pacc = 0.f;
#pragma unroll
    for (int it = 0; it < 6; ++it) {
        const int s = it * 4 + srow;
        float he[32];
#pragma unroll
        for (int q8 = 0; q8 < 8; ++q8) {
            const float4 rv = *(const float4*)&hid[s][q8 * 4];
            he[q8 * 4 + 0] = rv.x; he[q8 * 4 + 1] = rv.y;
            he[q8 * 4 + 2] = rv.z; he[q8 * 4 + 3] = rv.w;
        }
        float a = fb2v;
#pragma unroll
        for (int ff = 0; ff < 32; ++ff) a += he[ff] * f2c[ff];
        float xv = t1[s][d] + a;
        float sum = xv;
        sum += __shfl_xor(sum, 1); sum += __shfl_xor(sum, 2);
        sum += __shfl_xor(sum, 4); sum += __shfl_xor(sum, 8);
        const float mean = sum * 0.0625f;
        const float df = xv - mean;
        float v2 = df * df;
        v2 += __shfl_xor(v2, 1); v2 += __shfl_xor(v2, 2);
        v2 += __shfl_xor(v2, 4); v2 += __shfl_xor(v2, 8);
        const float var = v2 * 0.0625f;
        pacc += df * rsqrtf(var + 1e-3f) * g2v + be2v;
    }
    pacc += __shfl_xor(pacc, 16);
    pacc += __shfl_xor(pacc, 32);
    if (lane < 16) pooled[lane] = pacc * (1.0f / 24.0f);
    __syncthreads();

    float partial = 0.f;
    if (lane < 16) {
        float a = rb1[lane];
#pragma unroll
        for (int e = 0; e < 16; ++e) a += pooled[e] * rw1[e * 16 + lane];
        partial = gelu_exact(a) * rw2[lane];
    }
    partial += __shfl_xor(partial, 8);
    partial += __shfl_xor(partial, 4);
    partial += __shfl_xor(partial, 2);
    partial += __shfl_xor(partial, 1);
    if (lane == 0) outp[r] = partial + rb2[0];
}

extern "C" void kernel_launch(void* const* d_in, const int* in_sizes, int n_in,
                              void* d_out, int out_size, void* d_ws, size_t ws_size,
                              hipStream_t stream) {
    const float* x      = (const float*)d_in[0];
    const float* emb    = (const float*)d_in[1];
    const float* proj_w = (const float*)d_in[2];
    const float* proj_b = (const float*)d_in[3];
    const float* g1_w   = (const float*)d_in[4];
    const float* g1_as  = (const float*)d_in[5];
    const float* g1_ad  = (const float*)d_in[6];
    const float* g1_b   = (const float*)d_in[7];
    const float* g2_w   = (const float*)d_in[8];
    const float* g2_as  = (const float*)d_in[9];
    const float* g2_ad  = (const float*)d_in[10];
    const float* g2_b   = (const float*)d_in[11];
    const float* wq = (const float*)d_in[12];
    const float* bq = (const float*)d_in[13];
    const float* wk = (const float*)d_in[14];
    const float* bk = (const float*)d_in[15];
    const float* wv = (const float*)d_in[16];
    const float* bv = (const float*)d_in[17];
    const float* wo = (const float*)d_in[18];
    const float* bo = (const float*)d_in[19];
    const float* ln1g = (const float*)d_in[20];
    const float* ln1b = (const float*)d_in[21];
    const float* ln2g = (const float*)d_in[22];
    const float* ln2b = (const float*)d_in[23];
    const float* fw1 = (const float*)d_in[24];
    const float* fb1 = (const float*)d_in[25];
    const float* fw2 = (const float*)d_in[26];
    const float* fb2 = (const float*)d_in[27];
    const float* rw1 = (const float*)d_in[28];
    const float* rb1 = (const float*)d_in[29];
    const float* rw2 = (const float*)d_in[30];
    const float* rb2 = (const float*)d_in[31];

    // workspace layout
    unsigned short* nbr = (unsigned short*)d_ws;                  // 128,000 B (pad 131072)
    int* deg   = (int*)((char*)d_ws + 131072);                    // 2,000 B (pad 4096)
    float* h_g1  = (float*)((char*)d_ws + 135168);                // 1,536,000 B
    float* t_buf = (float*)((char*)d_ws + 135168 + 1536000);      // 3,072,000 B

    mask_kernel<<<500, 512, 0, stream>>>(emb, nbr, deg);
    gat_kernel<2, 8, true, true><<<384, 512, 0, stream>>>(
        x, proj_w, proj_b, g1_w, g1_as, g1_ad, g1_b, nbr, deg, h_g1);
    gat_kernel<4, 16, false, false><<<384, 512, 0, stream>>>(
        h_g1, nullptr, nullptr, g2_w, g2_as, g2_ad, g2_b, nbr, deg, t_buf);
    transformer_kernel<<<2000, 64, 0, stream>>>(
        t_buf, wq, bq, wk, bk, wv, bv, wo, bo, ln1g, ln1b, ln2g, ln2b,
        fw1, fb1, fw2, fb2, rw1, rb1, rw2, rb2, (float*)d_out);
}